// Round 6
// baseline (333.294 us; speedup 1.0000x reference)
//
#include <hip/hip_runtime.h>
#include <hip/hip_bf16.h>

// MetaNetImageEncoder on MI355X — round 9.
// Post-mortem r8: tail fusion/K-split regressed total 297->318 (gemm_pool
// identical 78.4) — REVERTED to r7 tail. gemm_pool floor update: MIX==non-MIX
// duration (per-iter work irrelevant) + VALUBusy 27% in the no-VALU non-MIX
// dispatch => ~87 VALU/wave/iter of ADDRESS RECOMPUTE (runtime mod-3/mod-2
// buffer indices defeat unrolling; sched_barriers pin it in-iteration).
// r9 gemm_pool: identical depth-2 counted-vmcnt schedule, but UNROLL-6
// (lcm of A-buf period 3, B-buf period 2) with compile-time buffer indices;
// 3 guard-free groups (kt 0..17) + peeled 6-iter tail; all ds_read/stage
// offsets hoisted to loop-invariant regs. Only issue overhead changes.
// Discriminator: VALUBusy must drop 27->~13%. If dur unchanged anyway, the
// floor is memory-latency congestion -> r10 = B-panel-in-LDS probe.
//
// MFMA 16x16x32 bf16 layouts (learn_hip m89):
//   A-frag: A[m=lane&15][k=(lane>>4)*8+j], B-frag: B[k=(lane>>4)*8+j][n=lane&15]
//   C/D:    col=lane&15, row=(lane>>4)*4+reg

typedef __bf16 bf16x8 __attribute__((ext_vector_type(8)));
typedef float f32x4 __attribute__((ext_vector_type(4)));
typedef __hip_bfloat16 bf16;

struct alignas(16) BF8 { bf16 h[8]; };

constexpr int BATCH = 64;
constexpr int NP    = 196;
constexpr int NPAD  = 256;
constexpr int DIM   = 768;
constexpr int NT    = 8;
constexpr size_t MSZ = (size_t)DIM * DIM;

__device__ __forceinline__ void async_cp16(const void* g, void* l) {
  __builtin_amdgcn_global_load_lds(
      (const __attribute__((address_space(1))) uint32_t*)g,
      (__attribute__((address_space(3))) uint32_t*)l, 16, 0, 0);
}

// ---------------- K1: patchify + cast to bf16, pad rows to 256 ----------------
__global__ void k_patchify(const float* __restrict__ x, bf16* __restrict__ A) {
  int idx  = blockIdx.x * blockDim.x + threadIdx.x;
  int col4 = idx % (DIM / 4);
  int row  = idx / (DIM / 4);
  int d = col4 * 4;
  int b = row >> 8;
  int n = row & 255;
  bf16 tmp[4];
  if (n < NP) {
    int hp = n / 14, wp = n % 14;
    int c  = d >> 8;
    int rr = d & 255;
    int i = rr >> 4, j = rr & 15;
    const float* src = x + ((((size_t)b * 3 + c) * 224 + hp * 16 + i) * 224 + wp * 16 + j);
    float4 f = *(const float4*)src;
    tmp[0] = __float2bfloat16(f.x);
    tmp[1] = __float2bfloat16(f.y);
    tmp[2] = __float2bfloat16(f.z);
    tmp[3] = __float2bfloat16(f.w);
  } else {
    tmp[0] = tmp[1] = tmp[2] = tmp[3] = __float2bfloat16(0.0f);
  }
  *(ushort4*)(A + (size_t)row * DIM + d) = *(ushort4*)tmp;
}

// ---------------- K2: transpose + cast weights: WT[mat][n][k] = W[mat][k][n] ----------------
__global__ void k_transpose_cast(const float* __restrict__ W1, const float* __restrict__ dW1,
                                 const float* __restrict__ W2, const float* __restrict__ dW2,
                                 bf16* __restrict__ WT) {
  __shared__ float tile[32][33];
  int mat = blockIdx.z;
  const float* src;
  if      (mat == 0) src = W1;
  else if (mat <= 8) src = dW1 + (size_t)(mat - 1) * MSZ;
  else if (mat == 9) src = W2;
  else               src = dW2 + (size_t)(mat - 10) * MSZ;
  int n0 = blockIdx.x * 32;
  int k0 = blockIdx.y * 32;
  int tx = threadIdx.x & 31, ty = threadIdx.x >> 5;
#pragma unroll
  for (int r = ty; r < 32; r += 8)
    tile[r][tx] = src[(size_t)(k0 + r) * DIM + n0 + tx];
  __syncthreads();
  bf16* dst = WT + (size_t)mat * MSZ;
#pragma unroll
  for (int r = ty; r < 32; r += 8)
    dst[(size_t)(n0 + r) * DIM + k0 + tx] = __float2bfloat16(tile[tx][r]);
}

// ---------------- K3: per-sample GEMM (+inline mix) + relu + masked column-mean --------------
// grid (64 samples, 12 n-tiles) = 768 blocks, 3 blocks/CU at 50KB LDS.
// BM=224, BN=64, BK=32, 24 k-iters. Depth-2 pipeline: A async 2 ahead
// (triple buf), B reg-staged 1 ahead (double buf). Raw s_barrier + counted
// vmcnt. UNROLL-6 with static buffer indices; offsets hoisted.
// Pair-granule swizzle: g(r,c) = (r>>1)*8 + ((4*(r&1)+c) ^ ((r>>1)&7)).
// Staging inverse for slot s: p=s>>3, u=(s&7)^(p&7), r=2p+(u>>2), c=u&3.

#define WAITVM(N) asm volatile("s_waitcnt vmcnt(" #N ")" ::: "memory")

template<int MIX>
__global__ __launch_bounds__(256, 3)
void k_gemm_pool(const bf16* __restrict__ A,    // [64*256, 768]
                 const bf16* __restrict__ WT,   // mats 0..8 = W1T, dW1T[8]
                 const float* __restrict__ b1,
                 const float* __restrict__ db1,
                 const float* __restrict__ coefs,  // [64][8] (MIX only)
                 float* __restrict__ pooled) {     // f32 [64][768]
  __shared__ uint4 AslU[3][896];   // 224 rows x 4 granules x 16B, x3 bufs = 42KB
  __shared__ uint4 BslU[2][256];   //  64 rows x 4 granules x 16B, x2 bufs =  8KB

  int b  = blockIdx.x;
  int n0 = blockIdx.y * 64;
  int tid = threadIdx.x;
  int wave = tid >> 6, lane = tid & 63;
  int quad = lane >> 4, l16 = lane & 15;

  float cr[NT];
  if (MIX) {
#pragma unroll
    for (int t = 0; t < NT; t++) cr[t] = coefs[b * NT + t];
  }

  const bf16* Ag = A + (size_t)b * NPAD * DIM;
  f32x4 acc[4][4] = {};

  // ---- hoisted A-stage source offsets (swizzle inverse baked in)
  int gbase = (wave < 2) ? wave * 256 : 512 + (wave - 2) * 192;
  int gcnt  = (wave < 2) ? 4 : 3;
  int aoff[4];
#pragma unroll
  for (int i = 0; i < 4; i++) {
    int s = gbase + i * 64 + lane;
    int p = s >> 3, u = (s & 7) ^ (p & 7);
    int r = 2 * p + (u >> 2), c = u & 3;
    aoff[i] = r * DIM + c * 8;
  }
  auto stage_a = [&](int buf, int kt) {
    const bf16* Ak = Ag + kt * 32;
#pragma unroll
    for (int i = 0; i < 4; i++) {
      if (i < gcnt)
        async_cp16(Ak + aoff[i], (void*)&AslU[buf][gbase + i * 64]);
    }
  };

  // ---- hoisted ds_read byte offsets (loop-invariant)
  auto gslot = [&](int row, int kq) {
    return (row >> 1) * 8 + ((4 * (row & 1) + kq) ^ ((row >> 1) & 7));
  };
  int boff[4], aoff_rd[4];
#pragma unroll
  for (int nf = 0; nf < 4; nf++) boff[nf] = gslot(nf * 16 + l16, quad) * 16;
#pragma unroll
  for (int mf = 0; mf < 4; mf++) aoff_rd[mf] = gslot(wave * 64 + mf * 16 + l16, quad) * 16;

  // ---- B reg-stage (T14): this thread owns LDS slot `tid`
  int bp = tid >> 3, bu = (tid & 7) ^ (bp & 7);
  int brow_st = 2 * bp + (bu >> 2), bcol_st = bu & 3;
  const bf16* Wrow = WT + (size_t)(n0 + brow_st) * DIM + bcol_st * 8;

  BF8 wreg[MIX ? 9 : 1];
  auto breg_load = [&](int kt) {
    const bf16* p0 = Wrow + kt * 32;
    wreg[0] = *(const BF8*)p0;
    if (MIX) {
#pragma unroll
      for (int t = 0; t < NT; t++)
        wreg[1 + t] = *(const BF8*)(p0 + (size_t)(1 + t) * MSZ);
    }
  };
  auto breg_write = [&](int buf) {
    if (MIX) {
      float m[8];
#pragma unroll
      for (int j = 0; j < 8; j++) m[j] = __bfloat162float(wreg[0].h[j]);
#pragma unroll
      for (int t = 0; t < NT; t++) {
        float cc = cr[t];
#pragma unroll
        for (int j = 0; j < 8; j++) m[j] += cc * __bfloat162float(wreg[1 + t].h[j]);
      }
      BF8 o;
#pragma unroll
      for (int j = 0; j < 8; j++) o.h[j] = __float2bfloat16(m[j]);
      BslU[buf][tid] = *(uint4*)&o;
    } else {
      BslU[buf][tid] = *(uint4*)&wreg[0];
    }
  };

  // ---- one pipeline iteration; AC/AS_/BC are compile-time literals
  // WMODE: 1 = counted vmcnt(4/3), 2 = vmcnt(0), 0 = none
#define GP_ITER(KT, AC, AS_, BC, DO_BREG, DO_STAGE, WMODE)                     \
  {                                                                            \
    __builtin_amdgcn_s_barrier();                                              \
    if (DO_BREG) breg_load((KT) + 1);                                          \
    __builtin_amdgcn_sched_barrier(0);                                         \
    if (DO_STAGE) stage_a(AS_, (KT) + 2);                                      \
    __builtin_amdgcn_sched_barrier(0);                                         \
    const char* Asb = (const char*)&AslU[AC][0];                               \
    const char* Bsb = (const char*)&BslU[BC][0];                               \
    bf16x8 bfr[4];                                                             \
    _Pragma("unroll")                                                          \
    for (int nf = 0; nf < 4; nf++) bfr[nf] = *(const bf16x8*)(Bsb + boff[nf]); \
    __builtin_amdgcn_s_setprio(1);                                             \
    _Pragma("unroll")                                                          \
    for (int mf = 0; mf < 4; mf++) {                                           \
      if (wave * 64 + mf * 16 < 224) {                                         \
        bf16x8 af = *(const bf16x8*)(Asb + aoff_rd[mf]);                       \
        _Pragma("unroll")                                                      \
        for (int nf = 0; nf < 4; nf++)                                         \
          acc[mf][nf] = __builtin_amdgcn_mfma_f32_16x16x32_bf16(               \
              af, bfr[nf], acc[mf][nf], 0, 0, 0);                              \
      }                                                                        \
    }                                                                          \
    __builtin_amdgcn_s_setprio(0);                                             \
    if (WMODE == 1) { if (wave < 2) WAITVM(4); else WAITVM(3); }               \
    else if (WMODE == 2) { WAITVM(0); }                                        \
    __builtin_amdgcn_sched_barrier(0);                                         \
    if (DO_BREG) {                                                             \
      breg_write((BC) ^ 1);                                                    \
      asm volatile("s_waitcnt lgkmcnt(0)" ::: "memory");                       \
    }                                                                          \
  }

  // ---- prologue: A tiles 0,1 in flight; B tile 0 mixed into buf 0
  stage_a(0, 0);
  stage_a(1, 1);
  breg_load(0);
  WAITVM(0);                         // prologue-only full drain
  __builtin_amdgcn_sched_barrier(0);
  breg_write(0);
  asm volatile("s_waitcnt lgkmcnt(0)" ::: "memory");

  // ---- main: 3 guard-free groups of 6 (kt = 0..17); bufA=kt%3, bufB=kt%2
  for (int g = 0; g < 3; g++) {
    int kt = g * 6;
    GP_ITER(kt + 0, 0, 2, 0, true, true, 1);
    GP_ITER(kt + 1, 1, 0, 1, true, true, 1);
    GP_ITER(kt + 2, 2, 1, 0, true, true, 1);
    GP_ITER(kt + 3, 0, 2, 1, true, true, 1);
    GP_ITER(kt + 4, 1, 0, 0, true, true, 1);
    GP_ITER(kt + 5, 2, 1, 1, true, true, 1);
  }
  // ---- peeled tail kt = 18..23
  GP_ITER(18, 0, 2, 0, true, true, 1);
  GP_ITER(19, 1, 0, 1, true, true, 1);
  GP_ITER(20, 2, 1, 0, true, true, 1);
  GP_ITER(21, 0, 2, 1, true, true, 1);    // stages tile 23 (last)
  GP_ITER(22, 1, 0, 0, true, false, 2);   // breg tile 23; full drain
  GP_ITER(23, 2, 1, 1, false, false, 0);  // last compute
#undef GP_ITER

  // ---- epilogue: relu(acc + bias), mask pad rows, column sums
  float* red = (float*)&BslU[0][0];   // overlays B buf 0 (last read @kt=22, drained)
  int m0 = wave * 64;
  float colsum[4];
#pragma unroll
  for (int nf = 0; nf < 4; nf++) {
    int col = n0 + nf * 16 + l16;
    float bias = b1[col];
    if (MIX) {
#pragma unroll
      for (int t = 0; t < NT; t++) bias += cr[t] * db1[t * DIM + col];
    }
    float s = 0.0f;
#pragma unroll
    for (int mf = 0; mf < 4; mf++) {
      int rbase = m0 + mf * 16 + quad * 4;
#pragma unroll
      for (int r = 0; r < 4; r++) {
        if (rbase + r < NP) s += fmaxf(acc[mf][nf][r] + bias, 0.0f);
      }
    }
    s += __shfl_xor(s, 16, 64);
    s += __shfl_xor(s, 32, 64);
    colsum[nf] = s;
  }
  if (lane < 16) {
#pragma unroll
    for (int nf = 0; nf < 4; nf++) red[wave * 64 + nf * 16 + lane] = colsum[nf];
  }
  __syncthreads();
  if (tid < 64) {
    float s = red[tid] + red[64 + tid] + red[128 + tid] + red[192 + tid];
    pooled[(size_t)b * DIM + n0 + tid] = s * (1.0f / 196.0f);
  }
}

// ---------------- K5: small GEMM, M=64: Y[mat] = Af(f32->bf16) @ WT[matbase+mat] ------------
__global__ __launch_bounds__(256, 2)
void k_gemm2(const float* __restrict__ Af,    // [64][768] f32
             const bf16* __restrict__ WT,
             int matbase,
             const float* __restrict__ bias,  // [768] or null
             float* __restrict__ Y) {         // [nmat][64][768]
  __shared__ uint4 AslU[64 * 8];
  __shared__ uint4 BslU[64 * 8];
  int n0  = blockIdx.x * 64;
  int mat = blockIdx.y;
  int tid = threadIdx.x, wave = tid >> 6, lane = tid & 63;
  int quad = lane >> 4, l16 = lane & 15;
  f32x4 acc[4] = {};
  const bf16* Wm = WT + (size_t)(matbase + mat) * MSZ;
  for (int k0 = 0; k0 < DIM; k0 += 64) {
#pragma unroll
    for (int i = 0; i < 2; i++) {
      int g = tid + i * 256;
      int r = g >> 3, c = g & 7;
      const float* src = Af + (size_t)r * DIM + k0 + c * 8;
      float4 xa = ((const float4*)src)[0];
      float4 xb = ((const float4*)src)[1];
      BF8 o;
      o.h[0] = __float2bfloat16(xa.x); o.h[1] = __float2bfloat16(xa.y);
      o.h[2] = __float2bfloat16(xa.z); o.h[3] = __float2bfloat16(xa.w);
      o.h[4] = __float2bfloat16(xb.x); o.h[5] = __float2bfloat16(xb.y);
      o.h[6] = __float2bfloat16(xb.z); o.h[7] = __float2bfloat16(xb.w);
      AslU[r * 8 + (c ^ (r & 7))] = *(uint4*)&o;
      BslU[r * 8 + (c ^ (r & 7))] = *(const uint4*)(Wm + (size_t)(n0 + r) * DIM + k0 + c * 8);
    }
    __syncthreads();
    const bf16* As = (const bf16*)AslU;
    const bf16* Bs = (const bf16*)BslU;
#pragma unroll
    for (int ks = 0; ks < 2; ks++) {
      int brow = wave * 16 + l16;
      bf16x8 bfr = *(const bf16x8*)(Bs + (size_t)(brow * 8 + ((ks * 4 + quad) ^ (brow & 7))) * 8);
#pragma unroll
      for (int mf = 0; mf < 4; mf++) {
        int arow = mf * 16 + l16;
        bf16x8 af = *(const bf16x8*)(As + (size_t)(arow * 8 + ((ks * 4 + quad) ^ (arow & 7))) * 8);
        acc[mf] = __builtin_amdgcn_mfma_f32_16x16x32_bf16(af, bfr, acc[mf], 0, 0, 0);
      }
    }
    __syncthreads();
  }
#pragma unroll
  for (int mf = 0; mf < 4; mf++) {
#pragma unroll
    for (int r = 0; r < 4; r++) {
      int row = mf * 16 + quad * 4 + r;
      int col = n0 + wave * 16 + l16;
      float v = acc[mf][r];
      if (bias) v += bias[col];
      Y[((size_t)mat * 64 + row) * DIM + col] = v;
    }
  }
}

// ---------------- K6: MetaNet: coefs = relu(base@mw1+mb1)@mw2 + mb2 ----------------
__global__ void k_metanet(const float* __restrict__ base,  // [64][768]
                          const float* __restrict__ mw1, const float* __restrict__ mb1,
                          const float* __restrict__ mw2, const float* __restrict__ mb2,
                          float* __restrict__ coefs) {     // [64][8]
  __shared__ float bl[DIM];
  __shared__ float hl[192];
  int b = blockIdx.x, tid = threadIdx.x;   // 192 threads
  for (int i = tid; i < DIM; i += 192) bl[i] = base[(size_t)b * DIM + i];
  __syncthreads();
  float s = mb1[tid];
  for (int k = 0; k < DIM; k++) s += bl[k] * mw1[(size_t)k * 192 + tid];
  hl[tid] = fmaxf(s, 0.0f);
  __syncthreads();
  if (tid < NT) {
    float c = mb2[tid];
    for (int j = 0; j < 192; j++) c += hl[j] * mw2[(size_t)j * NT + tid];
    coefs[b * NT + tid] = c;
  }
}

// ---------------- K7: combine: out = Y0 + b2 + sum_t c_t (Y[1+t] + db2_t) ----------------
__global__ void k_combine(const float* __restrict__ Y,
                          const float* __restrict__ coefs,
                          const float* __restrict__ b2,
                          const float* __restrict__ db2,
                          float* __restrict__ out) {
  int idx = blockIdx.x * 256 + threadIdx.x;
  int b = idx / DIM, e = idx % DIM;
  float v = Y[(size_t)b * DIM + e] + b2[e];
#pragma unroll
  for (int t = 0; t < NT; t++) {
    float c = coefs[b * NT + t];
    v += c * (Y[((size_t)(1 + t) * 64 + b) * DIM + e] + db2[(size_t)t * DIM + e]);
  }
  out[idx] = v;
}

extern "C" void kernel_launch(void* const* d_in, const int* in_sizes, int n_in,
                              void* d_out, int out_size, void* d_ws, size_t ws_size,
                              hipStream_t stream) {
  const float* x   = (const float*)d_in[0];
  const float* W1  = (const float*)d_in[1];
  const float* b1  = (const float*)d_in[2];
  const float* W2  = (const float*)d_in[3];
  const float* b2  = (const float*)d_in[4];
  const float* dW1 = (const float*)d_in[5];
  const float* db1 = (const float*)d_in[6];
  const float* dW2 = (const float*)d_in[7];
  const float* db2 = (const float*)d_in[8];
  const float* mw1 = (const float*)d_in[9];
  const float* mb1 = (const float*)d_in[10];
  const float* mw2 = (const float*)d_in[11];
  const float* mb2 = (const float*)d_in[12];
  float* out = (float*)d_out;
  (void)in_sizes; (void)n_in; (void)out_size; (void)ws_size;

  // workspace layout (bytes) — total ~48.8 MB
  char* ws = (char*)d_ws;
  bf16*  A_bf    = (bf16*) (ws);                 // 25,165,824
  bf16*  WT      = (bf16*) (ws + 25165824);      // 21,233,664 -> 46,399,488
  float* pooledA = (float*)(ws + 46399488);      //    196,608 -> 46,596,096
  float* pooledB = (float*)(ws + 46596096);      //    196,608 -> 46,792,704
  float* coefs   = (float*)(ws + 46792704);      //      2,048 -> 46,794,752
  float* base    = (float*)(ws + 46794752);      //    196,608 -> 46,991,360
  float* Y       = (float*)(ws + 46991360);      //  1,769,472 -> 48,760,832

  k_patchify<<<dim3((BATCH * NPAD * (DIM / 4)) / 256), 256, 0, stream>>>(x, A_bf);
  k_transpose_cast<<<dim3(24, 24, 18), 256, 0, stream>>>(W1, dW1, W2, dW2, WT);
  // phase A
  k_gemm_pool<0><<<dim3(BATCH, DIM / 64), 256, 0, stream>>>(A_bf, WT, b1, db1, nullptr, pooledA);
  k_gemm2<<<dim3(DIM / 64, 1), 256, 0, stream>>>(pooledA, WT, 9, b2, base);
  k_metanet<<<dim3(BATCH), 192, 0, stream>>>(base, mw1, mb1, mw2, mb2, coefs);
  // phase B (inline mix from L2-resident WT)
  k_gemm_pool<1><<<dim3(BATCH, DIM / 64), 256, 0, stream>>>(A_bf, WT, b1, db1, coefs, pooledB);
  k_gemm2<<<dim3(DIM / 64, 9), 256, 0, stream>>>(pooledB, WT, 9, nullptr, Y);
  k_combine<<<dim3((BATCH * DIM) / 256), 256, 0, stream>>>(Y, coefs, b2, db2, out);
}

// Round 7
// 285.191 us; speedup vs baseline: 1.1687x; 1.1687x over previous
//
#include <hip/hip_runtime.h>
#include <hip/hip_bf16.h>

// MetaNetImageEncoder on MI355X — round 10.
// Post-mortem r9: unroll-6 spilled (WRITE_SIZE 192KB->99MB tripwire, 78->112us)
// — REVERTED gemm_pool to the r8-measured body (78.4us, 0 conflicts). Five
// rounds of gemm_pool schedule surgery = one real win (r7); its ~7800cyc/iter
// floor defies the issue-level model, so stop gambling there. r10 spends the
// round on the ~140us tail with simple-arithmetic changes:
//  - k_prep: fused patchify + transpose_cast (independent, both memory-bound;
//    one launch, overlapped traffic).
//  - gemm2#1 K-split x4 (12->48 blocks, K=192 each) -> basep[4][64][768];
//    k_metanet sums partials + b2 (4 extra coalesced row reads).
//  - gemm_pool: byte-exact r8 body.
//
// MFMA 16x16x32 bf16 layouts (learn_hip m89):
//   A-frag: A[m=lane&15][k=(lane>>4)*8+j], B-frag: B[k=(lane>>4)*8+j][n=lane&15]
//   C/D:    col=lane&15, row=(lane>>4)*4+reg

typedef __bf16 bf16x8 __attribute__((ext_vector_type(8)));
typedef float f32x4 __attribute__((ext_vector_type(4)));
typedef __hip_bfloat16 bf16;

struct alignas(16) BF8 { bf16 h[8]; };

constexpr int BATCH = 64;
constexpr int NP    = 196;
constexpr int NPAD  = 256;
constexpr int DIM   = 768;
constexpr int NT    = 8;
constexpr size_t MSZ = (size_t)DIM * DIM;

__device__ __forceinline__ void async_cp16(const void* g, void* l) {
  __builtin_amdgcn_global_load_lds(
      (const __attribute__((address_space(1))) uint32_t*)g,
      (__attribute__((address_space(3))) uint32_t*)l, 16, 0, 0);
}

// ---------------- K1: fused patchify(+cast, pad) and weight transpose(+cast) ----------------
// blocks [0, 12288): patchify x -> A_bf [64*256][768] bf16
// blocks [12288, 22656): transpose 18 mats of 768x768: WT[mat][n][k] = W[mat][k][n]
constexpr int PREP_PATCH_BLOCKS = (BATCH * NPAD * (DIM / 4)) / 256;   // 12288
constexpr int PREP_TRANS_BLOCKS = 24 * 24 * 18;                       // 10368

__global__ void k_prep(const float* __restrict__ x, bf16* __restrict__ A,
                       const float* __restrict__ W1, const float* __restrict__ dW1,
                       const float* __restrict__ W2, const float* __restrict__ dW2,
                       bf16* __restrict__ WT) {
  __shared__ float tile[32][33];
  int blk = blockIdx.x;
  int tid = threadIdx.x;
  if (blk < PREP_PATCH_BLOCKS) {
    int idx  = blk * 256 + tid;
    int col4 = idx % (DIM / 4);
    int row  = idx / (DIM / 4);
    int d = col4 * 4;
    int b = row >> 8;
    int n = row & 255;
    bf16 tmp[4];
    if (n < NP) {
      int hp = n / 14, wp = n % 14;
      int c  = d >> 8;
      int rr = d & 255;
      int i = rr >> 4, j = rr & 15;
      const float* src = x + ((((size_t)b * 3 + c) * 224 + hp * 16 + i) * 224 + wp * 16 + j);
      float4 f = *(const float4*)src;
      tmp[0] = __float2bfloat16(f.x);
      tmp[1] = __float2bfloat16(f.y);
      tmp[2] = __float2bfloat16(f.z);
      tmp[3] = __float2bfloat16(f.w);
    } else {
      tmp[0] = tmp[1] = tmp[2] = tmp[3] = __float2bfloat16(0.0f);
    }
    *(ushort4*)(A + (size_t)row * DIM + d) = *(ushort4*)tmp;
  } else {
    int tb  = blk - PREP_PATCH_BLOCKS;
    int mat = tb / 576;
    int rem = tb % 576;
    int n0 = (rem % 24) * 32;
    int k0 = (rem / 24) * 32;
    const float* src;
    if      (mat == 0) src = W1;
    else if (mat <= 8) src = dW1 + (size_t)(mat - 1) * MSZ;
    else if (mat == 9) src = W2;
    else               src = dW2 + (size_t)(mat - 10) * MSZ;
    int tx = tid & 31, ty = tid >> 5;
#pragma unroll
    for (int r = ty; r < 32; r += 8)
      tile[r][tx] = src[(size_t)(k0 + r) * DIM + n0 + tx];
    __syncthreads();
    bf16* dst = WT + (size_t)mat * MSZ;
#pragma unroll
    for (int r = ty; r < 32; r += 8)
      dst[(size_t)(n0 + r) * DIM + k0 + tx] = __float2bfloat16(tile[tx][r]);
  }
}

// ---------------- K3: per-sample GEMM (+inline mix) + relu + masked column-mean --------------
// grid (64 samples, 12 n-tiles) = 768 blocks, 3 blocks/CU at 50KB LDS.
// BM=224 staged (rows>=196 zero pad; wave3 mf<2), BN=64, BK=32, 24 k-iters.
// Depth-2 pipeline: A async-staged 2 tiles ahead (triple buf), B reg-staged
// 1 tile ahead (double buf). Raw s_barrier + counted vmcnt — no full drain.
// Pair-granule swizzle: data(r,c) lives at LDS granule
//   g(r,c) = (r>>1)*8 + ((4*(r&1)+c) ^ ((r>>1)&7))       (granule = 16B)
// Staging inverse for slot s: p=s>>3, u=(s&7)^(p&7), r=2p+(u>>2), c=u&3.
// [r8-measured body: 78.4us, 0 bank conflicts, WRITE 192KB — do not touch]

#define WAITVM(N) asm volatile("s_waitcnt vmcnt(" #N ")" ::: "memory")

template<int MIX>
__global__ __launch_bounds__(256, 3)
void k_gemm_pool(const bf16* __restrict__ A,    // [64*256, 768]
                 const bf16* __restrict__ WT,   // mats 0..8 = W1T, dW1T[8]
                 const float* __restrict__ b1,
                 const float* __restrict__ db1,
                 const float* __restrict__ coefs,  // [64][8] (MIX only)
                 float* __restrict__ pooled) {     // f32 [64][768]
  __shared__ uint4 AslU[3][896];   // 224 rows x 4 granules x 16B, x3 bufs = 42KB
  __shared__ uint4 BslU[2][256];   //  64 rows x 4 granules x 16B, x2 bufs =  8KB

  int b  = blockIdx.x;
  int n0 = blockIdx.y * 64;
  int tid = threadIdx.x;
  int wave = tid >> 6, lane = tid & 63;
  int quad = lane >> 4, l16 = lane & 15;

  float cr[NT];
  if (MIX) {
#pragma unroll
    for (int t = 0; t < NT; t++) cr[t] = coefs[b * NT + t];
  }

  const bf16* Ag = A + (size_t)b * NPAD * DIM;
  f32x4 acc[4][4] = {};

  // ---- A stage: 896 granules; waves 0,1: 4 instrs, waves 2,3: 3 instrs
  // Per-lane source offsets hoisted out of the loop (swizzle inverse baked in).
  int gbase = (wave < 2) ? wave * 256 : 512 + (wave - 2) * 192;
  int gcnt  = (wave < 2) ? 4 : 3;
  int aoff[4];
#pragma unroll
  for (int i = 0; i < 4; i++) {
    int s = gbase + i * 64 + lane;
    int p = s >> 3, u = (s & 7) ^ (p & 7);
    int r = 2 * p + (u >> 2), c = u & 3;
    aoff[i] = r * DIM + c * 8;
  }
  auto stage_a = [&](int buf, int kt) {
    const bf16* Ak = Ag + kt * 32;
#pragma unroll
    for (int i = 0; i < 4; i++) {
      if (i < gcnt)
        async_cp16(Ak + aoff[i], (void*)&AslU[buf][gbase + i * 64]);
    }
  };

  // ---- B reg-stage (T14): this thread owns LDS slot `tid`
  int bp = tid >> 3, bu = (tid & 7) ^ (bp & 7);
  int brow_st = 2 * bp + (bu >> 2), bcol_st = bu & 3;
  const bf16* Wrow = WT + (size_t)(n0 + brow_st) * DIM + bcol_st * 8;

  BF8 wreg[MIX ? 9 : 1];
  auto breg_load = [&](int kt) {
    const bf16* p0 = Wrow + kt * 32;
    wreg[0] = *(const BF8*)p0;
    if (MIX) {
#pragma unroll
      for (int t = 0; t < NT; t++)
        wreg[1 + t] = *(const BF8*)(p0 + (size_t)(1 + t) * MSZ);
    }
  };
  auto breg_write = [&](int buf) {
    if (MIX) {
      float m[8];
#pragma unroll
      for (int j = 0; j < 8; j++) m[j] = __bfloat162float(wreg[0].h[j]);
#pragma unroll
      for (int t = 0; t < NT; t++) {
        float cc = cr[t];
#pragma unroll
        for (int j = 0; j < 8; j++) m[j] += cc * __bfloat162float(wreg[1 + t].h[j]);
      }
      BF8 o;
#pragma unroll
      for (int j = 0; j < 8; j++) o.h[j] = __float2bfloat16(m[j]);
      BslU[buf][tid] = *(uint4*)&o;
    } else {
      BslU[buf][tid] = *(uint4*)&wreg[0];
    }
  };

  auto gslot = [&](int row, int kq) {
    return (size_t)((row >> 1) * 8 + ((4 * (row & 1) + kq) ^ ((row >> 1) & 7)));
  };

  // ---- prologue: A tiles 0,1 in flight; B tile 0 mixed into buf 0
  stage_a(0, 0);
  stage_a(1, 1);
  breg_load(0);
  WAITVM(0);                         // prologue-only full drain
  __builtin_amdgcn_sched_barrier(0);
  breg_write(0);
  asm volatile("s_waitcnt lgkmcnt(0)" ::: "memory");

  // ---- K-loop: 24 iters, depth-2 counted pipeline
  int bufA = 0, stgA = 2, bufB = 0;
  for (int kt = 0; kt < 24; kt++) {
    __builtin_amdgcn_s_barrier();    // A[bufA], B[bufB] ready (end-of-prev guarantees)
    // issue B loads for tile kt+1 (pinned early)
    if (kt < 23) breg_load(kt + 1);
    __builtin_amdgcn_sched_barrier(0);
    // issue A stage for tile kt+2
    if (kt < 22) stage_a(stgA, kt + 2);
    __builtin_amdgcn_sched_barrier(0);
    // compute tile kt
    const bf16* As = (const bf16*)AslU[bufA];
    const bf16* Bs = (const bf16*)BslU[bufB];
    bf16x8 bfr[4];
#pragma unroll
    for (int nf = 0; nf < 4; nf++) {
      int brow = nf * 16 + l16;
      bfr[nf] = *(const bf16x8*)(Bs + gslot(brow, quad) * 8);
    }
    __builtin_amdgcn_s_setprio(1);   // T5: favor MFMA-entering wave
#pragma unroll
    for (int mf = 0; mf < 4; mf++) {
      if (wave * 64 + mf * 16 < 224) {   // wave-uniform; wave 3 does mf<2
        int arow = wave * 64 + mf * 16 + l16;
        bf16x8 af = *(const bf16x8*)(As + gslot(arow, quad) * 8);
#pragma unroll
        for (int nf = 0; nf < 4; nf++)
          acc[mf][nf] = __builtin_amdgcn_mfma_f32_16x16x32_bf16(af, bfr[nf], acc[mf][nf], 0, 0, 0);
      }
    }
    __builtin_amdgcn_s_setprio(0);
    // counted wait: completes A(kt+1) + breg(kt+1); leaves A(kt+2) in flight
    if (kt < 22) {
      if (wave < 2) WAITVM(4); else WAITVM(3);
    } else if (kt < 23) {
      WAITVM(0);
    }
    __builtin_amdgcn_sched_barrier(0);
    // mix + write B for tile kt+1; make durable before next barrier
    if (kt < 23) {
      breg_write(bufB ^ 1);
      asm volatile("s_waitcnt lgkmcnt(0)" ::: "memory");
    }
    bufA = (bufA == 2) ? 0 : bufA + 1;
    stgA = (stgA == 2) ? 0 : stgA + 1;
    bufB ^= 1;
  }

  // ---- epilogue: relu(acc + bias), mask pad rows, column sums
  float* red = (float*)&BslU[0][0];   // overlays B buf 0 (last read @kt=22, drained)
  int m0 = wave * 64;
  float colsum[4];
#pragma unroll
  for (int nf = 0; nf < 4; nf++) {
    int col = n0 + nf * 16 + l16;
    float bias = b1[col];
    if (MIX) {
#pragma unroll
      for (int t = 0; t < NT; t++) bias += cr[t] * db1[t * DIM + col];
    }
    float s = 0.0f;
#pragma unroll
    for (int mf = 0; mf < 4; mf++) {
      int rbase = m0 + mf * 16 + quad * 4;
#pragma unroll
      for (int r = 0; r < 4; r++) {
        if (rbase + r < NP) s += fmaxf(acc[mf][nf][r] + bias, 0.0f);
      }
    }
    s += __shfl_xor(s, 16, 64);
    s += __shfl_xor(s, 32, 64);
    colsum[nf] = s;
  }
  if (lane < 16) {
#pragma unroll
    for (int nf = 0; nf < 4; nf++) red[wave * 64 + nf * 16 + lane] = colsum[nf];
  }
  __syncthreads();
  if (tid < 64) {
    float s = red[tid] + red[64 + tid] + red[128 + tid] + red[192 + tid];
    pooled[(size_t)b * DIM + n0 + tid] = s * (1.0f / 196.0f);
  }
}

// ---------------- K5a: base partials, K-split x4: basep[kz] = Af[:,kz*192:+192] @ W2T[kz] ----
__global__ __launch_bounds__(256, 2)
void k_gemm2_ksplit(const float* __restrict__ Af,    // [64][768] f32 (pooledA)
                    const bf16* __restrict__ WT,     // mat 9 = W2T
                    float* __restrict__ basep) {     // [4][64][768]
  __shared__ uint4 AslU[64 * 8];
  __shared__ uint4 BslU[64 * 8];
  int n0  = blockIdx.x * 64;
  int kz  = blockIdx.y;
  int tid = threadIdx.x, wave = tid >> 6, lane = tid & 63;
  int quad = lane >> 4, l16 = lane & 15;
  f32x4 acc[4] = {};
  const bf16* Wm = WT + (size_t)9 * MSZ;
  for (int k0 = kz * 192; k0 < kz * 192 + 192; k0 += 64) {
#pragma unroll
    for (int i = 0; i < 2; i++) {
      int g = tid + i * 256;
      int r = g >> 3, c = g & 7;
      const float* src = Af + (size_t)r * DIM + k0 + c * 8;
      float4 xa = ((const float4*)src)[0];
      float4 xb = ((const float4*)src)[1];
      BF8 o;
      o.h[0] = __float2bfloat16(xa.x); o.h[1] = __float2bfloat16(xa.y);
      o.h[2] = __float2bfloat16(xa.z); o.h[3] = __float2bfloat16(xa.w);
      o.h[4] = __float2bfloat16(xb.x); o.h[5] = __float2bfloat16(xb.y);
      o.h[6] = __float2bfloat16(xb.z); o.h[7] = __float2bfloat16(xb.w);
      AslU[r * 8 + (c ^ (r & 7))] = *(uint4*)&o;
      BslU[r * 8 + (c ^ (r & 7))] = *(const uint4*)(Wm + (size_t)(n0 + r) * DIM + k0 + c * 8);
    }
    __syncthreads();
    const bf16* As = (const bf16*)AslU;
    const bf16* Bs = (const bf16*)BslU;
#pragma unroll
    for (int ks = 0; ks < 2; ks++) {
      int brow = wave * 16 + l16;
      bf16x8 bfr = *(const bf16x8*)(Bs + (size_t)(brow * 8 + ((ks * 4 + quad) ^ (brow & 7))) * 8);
#pragma unroll
      for (int mf = 0; mf < 4; mf++) {
        int arow = mf * 16 + l16;
        bf16x8 af = *(const bf16x8*)(As + (size_t)(arow * 8 + ((ks * 4 + quad) ^ (arow & 7))) * 8);
        acc[mf] = __builtin_amdgcn_mfma_f32_16x16x32_bf16(af, bfr, acc[mf], 0, 0, 0);
      }
    }
    __syncthreads();
  }
#pragma unroll
  for (int mf = 0; mf < 4; mf++) {
#pragma unroll
    for (int r = 0; r < 4; r++) {
      int row = mf * 16 + quad * 4 + r;
      int col = n0 + wave * 16 + l16;
      basep[((size_t)kz * 64 + row) * DIM + col] = acc[mf][r];
    }
  }
}

// ---------------- K5: small GEMM, M=64: Y[mat] = Af(f32->bf16) @ WT[matbase+mat] ------------
__global__ __launch_bounds__(256, 2)
void k_gemm2(const float* __restrict__ Af,    // [64][768] f32
             const bf16* __restrict__ WT,
             int matbase,
             const float* __restrict__ bias,  // [768] or null
             float* __restrict__ Y) {         // [nmat][64][768]
  __shared__ uint4 AslU[64 * 8];
  __shared__ uint4 BslU[64 * 8];
  int n0  = blockIdx.x * 64;
  int mat = blockIdx.y;
  int tid = threadIdx.x, wave = tid >> 6, lane = tid & 63;
  int quad = lane >> 4, l16 = lane & 15;
  f32x4 acc[4] = {};
  const bf16* Wm = WT + (size_t)(matbase + mat) * MSZ;
  for (int k0 = 0; k0 < DIM; k0 += 64) {
#pragma unroll
    for (int i = 0; i < 2; i++) {
      int g = tid + i * 256;
      int r = g >> 3, c = g & 7;
      const float* src = Af + (size_t)r * DIM + k0 + c * 8;
      float4 xa = ((const float4*)src)[0];
      float4 xb = ((const float4*)src)[1];
      BF8 o;
      o.h[0] = __float2bfloat16(xa.x); o.h[1] = __float2bfloat16(xa.y);
      o.h[2] = __float2bfloat16(xa.z); o.h[3] = __float2bfloat16(xa.w);
      o.h[4] = __float2bfloat16(xb.x); o.h[5] = __float2bfloat16(xb.y);
      o.h[6] = __float2bfloat16(xb.z); o.h[7] = __float2bfloat16(xb.w);
      AslU[r * 8 + (c ^ (r & 7))] = *(uint4*)&o;
      BslU[r * 8 + (c ^ (r & 7))] = *(const uint4*)(Wm + (size_t)(n0 + r) * DIM + k0 + c * 8);
    }
    __syncthreads();
    const bf16* As = (const bf16*)AslU;
    const bf16* Bs = (const bf16*)BslU;
#pragma unroll
    for (int ks = 0; ks < 2; ks++) {
      int brow = wave * 16 + l16;
      bf16x8 bfr = *(const bf16x8*)(Bs + (size_t)(brow * 8 + ((ks * 4 + quad) ^ (brow & 7))) * 8);
#pragma unroll
      for (int mf = 0; mf < 4; mf++) {
        int arow = mf * 16 + l16;
        bf16x8 af = *(const bf16x8*)(As + (size_t)(arow * 8 + ((ks * 4 + quad) ^ (arow & 7))) * 8);
        acc[mf] = __builtin_amdgcn_mfma_f32_16x16x32_bf16(af, bfr, acc[mf], 0, 0, 0);
      }
    }
    __syncthreads();
  }
#pragma unroll
  for (int mf = 0; mf < 4; mf++) {
#pragma unroll
    for (int r = 0; r < 4; r++) {
      int row = mf * 16 + quad * 4 + r;
      int col = n0 + wave * 16 + l16;
      float v = acc[mf][r];
      if (bias) v += bias[col];
      Y[((size_t)mat * 64 + row) * DIM + col] = v;
    }
  }
}

// ---------------- K6: MetaNet: coefs = relu((Σ_z basep + b2)@mw1+mb1)@mw2 + mb2 ------------
__global__ void k_metanet(const float* __restrict__ basep,  // [4][64][768]
                          const float* __restrict__ b2,
                          const float* __restrict__ mw1, const float* __restrict__ mb1,
                          const float* __restrict__ mw2, const float* __restrict__ mb2,
                          float* __restrict__ coefs) {      // [64][8]
  __shared__ float bl[DIM];
  __shared__ float hl[192];
  int b = blockIdx.x, tid = threadIdx.x;   // 192 threads
  const size_t ZS = (size_t)64 * DIM;
  for (int i = tid; i < DIM; i += 192) {
    size_t o = (size_t)b * DIM + i;
    bl[i] = basep[o] + basep[ZS + o] + basep[2 * ZS + o] + basep[3 * ZS + o] + b2[i];
  }
  __syncthreads();
  float s = mb1[tid];
  for (int k = 0; k < DIM; k++) s += bl[k] * mw1[(size_t)k * 192 + tid];
  hl[tid] = fmaxf(s, 0.0f);
  __syncthreads();
  if (tid < NT) {
    float c = mb2[tid];
    for (int j = 0; j < 192; j++) c += hl[j] * mw2[(size_t)j * NT + tid];
    coefs[b * NT + tid] = c;
  }
}

// ---------------- K7: combine: out = Y0 + b2 + sum_t c_t (Y[1+t] + db2_t) ----------------
__global__ void k_combine(const float* __restrict__ Y,
                          const float* __restrict__ coefs,
                          const float* __restrict__ b2,
                          const float* __restrict__ db2,
                          float* __restrict__ out) {
  int idx = blockIdx.x * 256 + threadIdx.x;
  int b = idx / DIM, e = idx % DIM;
  float v = Y[(size_t)b * DIM + e] + b2[e];
#pragma unroll
  for (int t = 0; t < NT; t++) {
    float c = coefs[b * NT + t];
    v += c * (Y[((size_t)(1 + t) * 64 + b) * DIM + e] + db2[(size_t)t * DIM + e]);
  }
  out[idx] = v;
}

extern "C" void kernel_launch(void* const* d_in, const int* in_sizes, int n_in,
                              void* d_out, int out_size, void* d_ws, size_t ws_size,
                              hipStream_t stream) {
  const float* x   = (const float*)d_in[0];
  const float* W1  = (const float*)d_in[1];
  const float* b1  = (const float*)d_in[2];
  const float* W2  = (const float*)d_in[3];
  const float* b2  = (const float*)d_in[4];
  const float* dW1 = (const float*)d_in[5];
  const float* db1 = (const float*)d_in[6];
  const float* dW2 = (const float*)d_in[7];
  const float* db2 = (const float*)d_in[8];
  const float* mw1 = (const float*)d_in[9];
  const float* mb1 = (const float*)d_in[10];
  const float* mw2 = (const float*)d_in[11];
  const float* mb2 = (const float*)d_in[12];
  float* out = (float*)d_out;
  (void)in_sizes; (void)n_in; (void)out_size; (void)ws_size;

  // workspace layout (bytes) — total ~49.4 MB
  char* ws = (char*)d_ws;
  bf16*  A_bf    = (bf16*) (ws);                 // 25,165,824
  bf16*  WT      = (bf16*) (ws + 25165824);      // 21,233,664 -> 46,399,488
  float* pooledA = (float*)(ws + 46399488);      //    196,608 -> 46,596,096
  float* pooledB = (float*)(ws + 46596096);      //    196,608 -> 46,792,704
  float* coefs   = (float*)(ws + 46792704);      //      2,048 -> 46,794,752
  float* basep   = (float*)(ws + 46794752);      //    786,432 -> 47,581,184
  float* Y       = (float*)(ws + 47581184);      //  1,769,472 -> 49,350,656

  k_prep<<<dim3(PREP_PATCH_BLOCKS + PREP_TRANS_BLOCKS), 256, 0, stream>>>(
      x, A_bf, W1, dW1, W2, dW2, WT);
  // phase A
  k_gemm_pool<0><<<dim3(BATCH, DIM / 64), 256, 0, stream>>>(A_bf, WT, b1, db1, nullptr, pooledA);
  k_gemm2_ksplit<<<dim3(DIM / 64, 4), 256, 0, stream>>>(pooledA, WT, basep);
  k_metanet<<<dim3(BATCH), 192, 0, stream>>>(basep, b2, mw1, mb1, mw2, mb2, coefs);
  // phase B (inline mix from L2-resident WT)
  k_gemm_pool<1><<<dim3(BATCH, DIM / 64), 256, 0, stream>>>(A_bf, WT, b1, db1, coefs, pooledB);
  k_gemm2<<<dim3(DIM / 64, 9), 256, 0, stream>>>(pooledB, WT, 9, nullptr, Y);
  k_combine<<<dim3((BATCH * DIM) / 256), 256, 0, stream>>>(Y, coefs, b2, db2, out);
}